// Round 9
// baseline (914.309 us; speedup 1.0000x reference)
//
#include <hip/hip_runtime.h>
#include <cstdio>

#define FIN 6
#define HC 64
#define LAYERS 3

// monotone float<->uint map (order-preserving) for atomicMax on signed floats
static __device__ __forceinline__ unsigned int fenc(float f) {
  unsigned int u = __float_as_uint(f);
  return (u & 0x80000000u) ? ~u : (u | 0x80000000u);
}
static __device__ __forceinline__ float fdec(unsigned int u) {
  return __uint_as_float((u & 0x80000000u) ? (u & 0x7FFFFFFFu) : ~u);
}
#define AGG_INIT 0x007FFFFFu  // fenc(-inf)

__global__ void PathfindingGNN_17274358464713_kernel() {}

__global__ __launch_bounds__(256) void k_zero(int* __restrict__ p, int n) {
  int i = blockIdx.x * 256 + threadIdx.x;
  if (i < n) p[i] = 0;
}

// ---------------- encoder: h0 = x @ W_enc + b_enc ----------------
__global__ __launch_bounds__(256) void k_encode(const float* __restrict__ x,
                                                const float* __restrict__ W,
                                                const float* __restrict__ b,
                                                float* __restrict__ h, int Nn) {
  int idx = blockIdx.x * 256 + threadIdx.x;
  if (idx >= Nn * HC) return;
  int n = idx >> 6, c = idx & 63;
  float s = b[c];
#pragma unroll
  for (int f = 0; f < FIN; ++f)
    s = fmaf(x[n * FIN + f], W[f * HC + c], s);
  h[idx] = s;
}

// ---------------- CSR build ----------------
__global__ __launch_bounds__(256) void k_hist(const int* __restrict__ dst, int* __restrict__ counts, int E) {
  int e = blockIdx.x * 256 + threadIdx.x;
  if (e < E) atomicAdd(&counts[dst[e]], 1);
}

__global__ __launch_bounds__(256) void k_scan1(const int* __restrict__ counts, int* __restrict__ partial,
                                               int* __restrict__ blockSums, int n) {
  __shared__ int lds[256];
  int tid = threadIdx.x;
  int base = blockIdx.x * 2048 + tid * 8;
  int v[8], e[8], s = 0;
#pragma unroll
  for (int j = 0; j < 8; ++j) {
    v[j] = (base + j < n) ? counts[base + j] : 0;
    e[j] = s;
    s += v[j];
  }
  lds[tid] = s;
  __syncthreads();
  for (int d = 1; d < 256; d <<= 1) {
    int t = (tid >= d) ? lds[tid - d] : 0;
    __syncthreads();
    lds[tid] += t;
    __syncthreads();
  }
  int off = (tid == 0) ? 0 : lds[tid - 1];
#pragma unroll
  for (int j = 0; j < 8; ++j)
    if (base + j < n) partial[base + j] = off + e[j];
  if (tid == 0) blockSums[blockIdx.x] = lds[255];
}

__global__ __launch_bounds__(256) void k_scan2(const int* __restrict__ blockSums, int* __restrict__ blockOff, int nb) {
  __shared__ int lds[256];
  int tid = threadIdx.x;
  lds[tid] = (tid < nb) ? blockSums[tid] : 0;
  __syncthreads();
  for (int d = 1; d < 256; d <<= 1) {
    int t = (tid >= d) ? lds[tid - d] : 0;
    __syncthreads();
    lds[tid] += t;
    __syncthreads();
  }
  if (tid < nb) blockOff[tid] = (tid == 0) ? 0 : lds[tid - 1];
}

__global__ __launch_bounds__(256) void k_scan3(int* __restrict__ rp, const int* __restrict__ boff,
                                               int* __restrict__ cursor, int n, int total) {
  int i = blockIdx.x * 256 + threadIdx.x;
  if (i > n) return;
  int v = (i == n) ? total : rp[i] + boff[i >> 11];
  rp[i] = v;
  cursor[i] = v;
}

// pack (src | dst_local<<20, ea_bits) -- valid while Nn < 2^20 (here Nn = 100000)
__global__ __launch_bounds__(256) void k_scatter(const int* __restrict__ src, const int* __restrict__ dst,
                                                 const float* __restrict__ ea, int* __restrict__ cursor,
                                                 int2* __restrict__ csr_se, int E) {
  int e = blockIdx.x * 256 + threadIdx.x;
  if (e >= E) return;
  int d = dst[e];
  int p = atomicAdd(&cursor[d], 1);
  csr_se[p] = make_int2(src[e] | ((d & 63) << 20), __float_as_int(ea[e]));
}

// ---------------- fused layer: edge-parallel aggregate (LDS atomicMax) + GEMM + BN --------
// 64 nodes/block, 256 threads. LDS: Asm 17,408B + Wsm 16,384B = 33,792B.
// Aggregate: block's CSR edge range strip-mined by all 4 waves (lane = channel),
// msgs max-combined via ds atomic max on fenc-encoded uints -> deep MLP on gathers.
__global__ __launch_bounds__(256) void k_layer(const float* __restrict__ h, const int* __restrict__ row_ptr,
                                               const int2* __restrict__ csr_se,
                                               const float* __restrict__ We, const float* __restrict__ be,
                                               const float* __restrict__ W, const float* __restrict__ b,
                                               const float* __restrict__ gam, const float* __restrict__ bet,
                                               const float* __restrict__ mean, const float* __restrict__ var,
                                               float* __restrict__ out, int Nn) {
  __shared__ float Asm[64][68];
  __shared__ float Wsm[64][64];
  int tid = threadIdx.x;
  int nb = blockIdx.x * 64;
  int c = tid & 63, w = tid >> 6;
  unsigned int* AsmU = (unsigned int*)&Asm[0][0];

  // init agg accumulators to fenc(-inf); stage W rows 64..127 (agg half)
  for (int j = tid; j < 4096; j += 256) AsmU[(j >> 6) * 68 + (j & 63)] = AGG_INIT;
  for (int i = tid; i < 4096; i += 256) Wsm[i >> 6][i & 63] = W[4096 + i];
  __syncthreads();

  float we = We[c], bev = be[c];
  {
    int r0b = row_ptr[nb];
    int r1b = row_ptr[min(nb + 64, Nn)];
    int r = r0b + w;
    for (; r + 4 < r1b; r += 8) {  // 2 independent gathers in flight per wave
      int2 ra = csr_se[r], rb = csr_se[r + 4];
      float ha = h[(ra.x & 0xFFFFF) * HC + c];
      float hb = h[(rb.x & 0xFFFFF) * HC + c];
      float ma = ha * fmaf(__int_as_float(ra.y), we, bev);
      float mb = hb * fmaf(__int_as_float(rb.y), we, bev);
      atomicMax(&AsmU[(ra.x >> 20) * 68 + c], fenc(ma));
      atomicMax(&AsmU[(rb.x >> 20) * 68 + c], fenc(mb));
    }
    for (; r < r1b; r += 4) {
      int2 ra = csr_se[r];
      float ha = h[(ra.x & 0xFFFFF) * HC + c];
      float ma = ha * fmaf(__int_as_float(ra.y), we, bev);
      atomicMax(&AsmU[(ra.x >> 20) * 68 + c], fenc(ma));
    }
  }
  __syncthreads();
  // decode in place; empty segment -> 0
  for (int j = tid; j < 4096; j += 256) {
    int p = (j >> 6) * 68 + (j & 63);
    unsigned int u = AsmU[p];
    Asm[0][p] = (u == AGG_INIT) ? 0.0f : fdec(u);
  }
  __syncthreads();

  // GEMM phase 0: acc += agg @ W[64..127]
  int c0 = (tid & 15) * 4, n0 = (tid >> 4) * 4;
  float acc[4][4] = {{0.f}};
#pragma unroll 4
  for (int k = 0; k < 64; k += 4) {
    float a[4][4], wv[4][4];
#pragma unroll
    for (int j = 0; j < 4; ++j) {
      float4 t = *(const float4*)&Asm[n0 + j][k];
      a[j][0] = t.x; a[j][1] = t.y; a[j][2] = t.z; a[j][3] = t.w;
    }
#pragma unroll
    for (int j = 0; j < 4; ++j) {
      float4 t = *(const float4*)&Wsm[k + j][c0];
      wv[j][0] = t.x; wv[j][1] = t.y; wv[j][2] = t.z; wv[j][3] = t.w;
    }
#pragma unroll
    for (int i = 0; i < 4; ++i)
#pragma unroll
      for (int j = 0; j < 4; ++j)
#pragma unroll
        for (int l = 0; l < 4; ++l)
          acc[i][l] = fmaf(a[i][j], wv[j][l], acc[i][l]);
  }
  __syncthreads();

  // GEMM phase 1: restage Asm = h(self), Wsm = W rows 0..63
  for (int i = tid; i < 4096; i += 256) Wsm[i >> 6][i & 63] = W[i];
#pragma unroll
  for (int i = 0; i < 16; ++i) {
    int nl = i * 4 + w;
    int ng = min(nb + nl, Nn - 1);
    Asm[nl][c] = h[ng * HC + c];
  }
  __syncthreads();
#pragma unroll 4
  for (int k = 0; k < 64; k += 4) {
    float a[4][4], wv[4][4];
#pragma unroll
    for (int j = 0; j < 4; ++j) {
      float4 t = *(const float4*)&Asm[n0 + j][k];
      a[j][0] = t.x; a[j][1] = t.y; a[j][2] = t.z; a[j][3] = t.w;
    }
#pragma unroll
    for (int j = 0; j < 4; ++j) {
      float4 t = *(const float4*)&Wsm[k + j][c0];
      wv[j][0] = t.x; wv[j][1] = t.y; wv[j][2] = t.z; wv[j][3] = t.w;
    }
#pragma unroll
    for (int i = 0; i < 4; ++i)
#pragma unroll
      for (int j = 0; j < 4; ++j)
#pragma unroll
        for (int l = 0; l < 4; ++l)
          acc[i][l] = fmaf(a[i][j], wv[j][l], acc[i][l]);
  }

  float scale[4], shift[4], bias[4];
#pragma unroll
  for (int l = 0; l < 4; ++l) {
    int cc = c0 + l;
    bias[l] = b[cc];
    float sc = gam[cc] * rsqrtf(var[cc] + 1e-5f);
    scale[l] = sc;
    shift[l] = bet[cc] - mean[cc] * sc;
  }
#pragma unroll
  for (int i = 0; i < 4; ++i) {
    int n = nb + n0 + i;
    if (n < Nn) {
      float4 o;
      float v;
      v = fmaxf(acc[i][0] + bias[0], 0.f); o.x = fmaxf(fmaf(v, scale[0], shift[0]), 0.f);
      v = fmaxf(acc[i][1] + bias[1], 0.f); o.y = fmaxf(fmaf(v, scale[1], shift[1]), 0.f);
      v = fmaxf(acc[i][2] + bias[2], 0.f); o.z = fmaxf(fmaf(v, scale[2], shift[2]), 0.f);
      v = fmaxf(acc[i][3] + bias[3], 0.f); o.w = fmaxf(fmaf(v, scale[3], shift[3]), 0.f);
      *(float4*)&out[n * HC + c0] = o;
    }
  }
}

// ---------------- fused predictor: out = relu(h @ Wp1 + b1) @ Wp2 + b2 ----------------
__global__ __launch_bounds__(256) void k_predict(const float* __restrict__ h, const float* __restrict__ Wp1,
                                                 const float* __restrict__ bp1, const float* __restrict__ Wp2,
                                                 const float* __restrict__ bp2, float* __restrict__ out, int Nn) {
  __shared__ float Asm[64][68];
  __shared__ float Wsm[64][64];
  __shared__ float red[64][17];
  int tid = threadIdx.x;
  int nb = blockIdx.x * 64;
  for (int i = tid; i < 64 * 64; i += 256) Wsm[i >> 6][i & 63] = Wp1[i];
  int c = tid & 63, w = tid >> 6;
#pragma unroll
  for (int i = 0; i < 16; ++i) {
    int nl = i * 4 + w;
    int ng = min(nb + nl, Nn - 1);
    Asm[nl][c] = h[ng * HC + c];
  }
  __syncthreads();
  int c0 = (tid & 15) * 4, n0 = (tid >> 4) * 4;
  float acc[4][4] = {{0.f}};
#pragma unroll 4
  for (int k = 0; k < 64; k += 4) {
    float a[4][4], wv[4][4];
#pragma unroll
    for (int j = 0; j < 4; ++j) {
      float4 t = *(const float4*)&Asm[n0 + j][k];
      a[j][0] = t.x; a[j][1] = t.y; a[j][2] = t.z; a[j][3] = t.w;
    }
#pragma unroll
    for (int j = 0; j < 4; ++j) {
      float4 t = *(const float4*)&Wsm[k + j][c0];
      wv[j][0] = t.x; wv[j][1] = t.y; wv[j][2] = t.z; wv[j][3] = t.w;
    }
#pragma unroll
    for (int i = 0; i < 4; ++i)
#pragma unroll
      for (int j = 0; j < 4; ++j)
#pragma unroll
        for (int l = 0; l < 4; ++l)
          acc[i][l] = fmaf(a[i][j], wv[j][l], acc[i][l]);
  }
  float bias[4], w2[4];
#pragma unroll
  for (int l = 0; l < 4; ++l) {
    bias[l] = bp1[c0 + l];
    w2[l] = Wp2[c0 + l];
  }
#pragma unroll
  for (int i = 0; i < 4; ++i) {
    float s = 0.f;
#pragma unroll
    for (int l = 0; l < 4; ++l) {
      float t = fmaxf(acc[i][l] + bias[l], 0.f);
      s = fmaf(t, w2[l], s);
    }
    red[n0 + i][tid & 15] = s;
  }
  __syncthreads();
  if (tid < 64) {
    float s = bp2[0];
#pragma unroll
    for (int g = 0; g < 16; ++g) s += red[tid][g];
    int n = nb + tid;
    if (n < Nn) out[n] = s;
  }
}

extern "C" void kernel_launch(void* const* d_in, const int* in_sizes, int n_in,
                              void* d_out, int out_size, void* d_ws, size_t ws_size,
                              hipStream_t stream) {
  const float* x = (const float*)d_in[0];
  const int* eidx = (const int*)d_in[1];
  const float* eattr = (const float*)d_in[2];
  const float* Wenc = (const float*)d_in[3];
  const float* benc = (const float*)d_in[4];
  const float* Wedge = (const float*)d_in[5];
  const float* bedge = (const float*)d_in[6];
  const float* Wupd = (const float*)d_in[7];
  const float* bupd = (const float*)d_in[8];
  const float* bng = (const float*)d_in[9];
  const float* bnb = (const float*)d_in[10];
  const float* bnm = (const float*)d_in[11];
  const float* bnv = (const float*)d_in[12];
  const float* Wp1 = (const float*)d_in[13];
  const float* bp1 = (const float*)d_in[14];
  const float* Wp2 = (const float*)d_in[15];
  const float* bp2 = (const float*)d_in[16];

  const int Nn = in_sizes[0] / FIN;
  const int E = in_sizes[1] / 2;
  const int* src = eidx;
  const int* dst = eidx + E;
  const int NH = Nn * HC;

  size_t off = 0;
  char* base = (char*)d_ws;
  auto carve = [&](size_t bytes) -> void* {
    void* p = base + off;
    off += (bytes + 255) & ~(size_t)255;
    return p;
  };
  int* row_ptr = (int*)carve((size_t)(Nn + 1) * 4);
  int* cursor = (int*)carve((size_t)(Nn + 1) * 4);
  int* counts = (int*)carve((size_t)(Nn + 1) * 4);
  int* bsums = (int*)carve(256 * 4);
  int* boffs = (int*)carve(256 * 4);
  int2* csr_se = (int2*)carve((size_t)E * 8);
  float* hA = (float*)carve((size_t)NH * 4);
  float* hB = (float*)carve((size_t)NH * 4);
  if (off > ws_size) {
    fprintf(stderr, "[DIAG] WS too small %zu > %zu\n", off, ws_size);
    return;
  }

  int nhB = (NH + 255) / 256;
  int histB = (E + 255) / 256;
  int scan1B = (Nn + 2047) / 2048;
  int scan3B = (Nn + 1 + 255) / 256;
  int updB = (Nn + 63) / 64;

  k_zero<<<scan3B, 256, 0, stream>>>(counts, Nn + 1);
  k_encode<<<nhB, 256, 0, stream>>>(x, Wenc, benc, hA, Nn);
  k_hist<<<histB, 256, 0, stream>>>(dst, counts, E);
  k_scan1<<<scan1B, 256, 0, stream>>>(counts, row_ptr, bsums, Nn);
  k_scan2<<<1, 256, 0, stream>>>(bsums, boffs, scan1B);
  k_scan3<<<scan3B, 256, 0, stream>>>(row_ptr, boffs, cursor, Nn, E);
  k_scatter<<<histB, 256, 0, stream>>>(src, dst, eattr, cursor, csr_se, E);

  float* hc = hA;
  float* hn = hB;
  for (int i = 0; i < LAYERS; ++i) {
    k_layer<<<updB, 256, 0, stream>>>(hc, row_ptr, csr_se,
                                      Wedge + i * HC, bedge + i * HC,
                                      Wupd + i * 2 * HC * HC, bupd + i * HC,
                                      bng + i * HC, bnb + i * HC, bnm + i * HC, bnv + i * HC,
                                      hn, Nn);
    float* t = hc; hc = hn; hn = t;
  }
  k_predict<<<updB, 256, 0, stream>>>(hc, Wp1, bp1, Wp2, bp2, (float*)d_out, Nn);
}

// Round 10
// 620.537 us; speedup vs baseline: 1.4734x; 1.4734x over previous
//
#include <hip/hip_runtime.h>

#define FIN 6
#define HC 64
#define LAYERS 3

__global__ void PathfindingGNN_17274358464713_kernel() {}

__global__ __launch_bounds__(256) void k_zero(int* __restrict__ p, int n) {
  int i = blockIdx.x * 256 + threadIdx.x;
  if (i < n) p[i] = 0;
}

// ---------------- encoder: h0 = x @ W_enc + b_enc ----------------
__global__ __launch_bounds__(256) void k_encode(const float* __restrict__ x,
                                                const float* __restrict__ W,
                                                const float* __restrict__ b,
                                                float* __restrict__ h, int Nn) {
  int idx = blockIdx.x * 256 + threadIdx.x;
  if (idx >= Nn * HC) return;
  int n = idx >> 6, c = idx & 63;
  float s = b[c];
#pragma unroll
  for (int f = 0; f < FIN; ++f)
    s = fmaf(x[n * FIN + f], W[f * HC + c], s);
  h[idx] = s;
}

// ---------------- CSR build ----------------
__global__ __launch_bounds__(256) void k_hist(const int* __restrict__ dst, int* __restrict__ counts, int E) {
  int e = blockIdx.x * 256 + threadIdx.x;
  if (e < E) atomicAdd(&counts[dst[e]], 1);
}

__global__ __launch_bounds__(256) void k_scan1(const int* __restrict__ counts, int* __restrict__ partial,
                                               int* __restrict__ blockSums, int n) {
  __shared__ int lds[256];
  int tid = threadIdx.x;
  int base = blockIdx.x * 2048 + tid * 8;
  int v[8], e[8], s = 0;
#pragma unroll
  for (int j = 0; j < 8; ++j) {
    v[j] = (base + j < n) ? counts[base + j] : 0;
    e[j] = s;
    s += v[j];
  }
  lds[tid] = s;
  __syncthreads();
  for (int d = 1; d < 256; d <<= 1) {
    int t = (tid >= d) ? lds[tid - d] : 0;
    __syncthreads();
    lds[tid] += t;
    __syncthreads();
  }
  int off = (tid == 0) ? 0 : lds[tid - 1];
#pragma unroll
  for (int j = 0; j < 8; ++j)
    if (base + j < n) partial[base + j] = off + e[j];
  if (tid == 0) blockSums[blockIdx.x] = lds[255];
}

__global__ __launch_bounds__(256) void k_scan2(const int* __restrict__ blockSums, int* __restrict__ blockOff, int nb) {
  __shared__ int lds[256];
  int tid = threadIdx.x;
  lds[tid] = (tid < nb) ? blockSums[tid] : 0;
  __syncthreads();
  for (int d = 1; d < 256; d <<= 1) {
    int t = (tid >= d) ? lds[tid - d] : 0;
    __syncthreads();
    lds[tid] += t;
    __syncthreads();
  }
  if (tid < nb) blockOff[tid] = (tid == 0) ? 0 : lds[tid - 1];
}

__global__ __launch_bounds__(256) void k_scan3(int* __restrict__ rp, const int* __restrict__ boff,
                                               int* __restrict__ cursor, int n, int total) {
  int i = blockIdx.x * 256 + threadIdx.x;
  if (i > n) return;
  int v = (i == n) ? total : rp[i] + boff[i >> 11];
  rp[i] = v;
  cursor[i] = v;
}

// pack (src, ea_bits): one 8B wave-uniform load per edge in the hot loop
__global__ __launch_bounds__(256) void k_scatter(const int* __restrict__ src, const int* __restrict__ dst,
                                                 const float* __restrict__ ea, int* __restrict__ cursor,
                                                 int2* __restrict__ csr_se, int E) {
  int e = blockIdx.x * 256 + threadIdx.x;
  if (e >= E) return;
  int d = dst[e];
  int p = atomicAdd(&cursor[d], 1);
  csr_se[p] = make_int2(src[e], __float_as_int(ea[e]));
}

// ---------------- fused layer: CSR aggregate-max + update GEMM + BN (+predictor on last) ----
// 64 nodes/block, 256 threads. LDS: Asm 17,408 + Wsm 16,384 + red 4,352 = 38,144B -> 4 blk/CU.
// Aggregate: wave-per-node serial edge loop, 4 independent max chains (R8 structure, deeper).
__global__ __launch_bounds__(256) void k_layer(const float* __restrict__ h, const int* __restrict__ row_ptr,
                                               const int2* __restrict__ csr_se,
                                               const float* __restrict__ We, const float* __restrict__ be,
                                               const float* __restrict__ W, const float* __restrict__ b,
                                               const float* __restrict__ gam, const float* __restrict__ bet,
                                               const float* __restrict__ mean, const float* __restrict__ var,
                                               float* __restrict__ out, int Nn,
                                               int last, const float* __restrict__ Wp1,
                                               const float* __restrict__ bp1, const float* __restrict__ Wp2,
                                               const float* __restrict__ bp2, float* __restrict__ pred) {
  __shared__ float Asm[64][68];
  __shared__ float Wsm[64][64];
  __shared__ float red[64][17];
  int tid = threadIdx.x;
  int nb = blockIdx.x * 64;
  int c = tid & 63, w = tid >> 6;

  // stage W rows 64..127 (agg half) while gathers run
  for (int i = tid; i < 4096; i += 256) Wsm[i >> 6][i & 63] = W[4096 + i];

  float we = We[c], bev = be[c];
  for (int i = 0; i < 16; ++i) {
    int nl = w * 16 + i;
    int nc = min(nb + nl, Nn - 1);
    int r0 = row_ptr[nc], r1 = row_ptr[nc + 1];
    float m0 = -INFINITY, m1 = -INFINITY, m2 = -INFINITY, m3 = -INFINITY;
    int r = r0;
    for (; r + 3 < r1; r += 4) {  // 4 independent gathers in flight
      int2 ra = csr_se[r], rb = csr_se[r + 1], rc = csr_se[r + 2], rd = csr_se[r + 3];
      float ha = h[ra.x * HC + c];
      float hb = h[rb.x * HC + c];
      float hc2 = h[rc.x * HC + c];
      float hd = h[rd.x * HC + c];
      m0 = fmaxf(m0, ha * fmaf(__int_as_float(ra.y), we, bev));
      m1 = fmaxf(m1, hb * fmaf(__int_as_float(rb.y), we, bev));
      m2 = fmaxf(m2, hc2 * fmaf(__int_as_float(rc.y), we, bev));
      m3 = fmaxf(m3, hd * fmaf(__int_as_float(rd.y), we, bev));
    }
    for (; r < r1; ++r) {
      int2 ra = csr_se[r];
      m0 = fmaxf(m0, h[ra.x * HC + c] * fmaf(__int_as_float(ra.y), we, bev));
    }
    float m = fmaxf(fmaxf(m0, m1), fmaxf(m2, m3));
    Asm[nl][c] = (m == -INFINITY) ? 0.0f : m;  // empty segment -> 0
  }
  __syncthreads();

  // GEMM phase 0: acc += agg @ W[64..127]
  int c0 = (tid & 15) * 4, n0 = (tid >> 4) * 4;
  float acc[4][4] = {{0.f}};
#pragma unroll 4
  for (int k = 0; k < 64; k += 4) {
    float a[4][4], wv[4][4];
#pragma unroll
    for (int j = 0; j < 4; ++j) {
      float4 t = *(const float4*)&Asm[n0 + j][k];
      a[j][0] = t.x; a[j][1] = t.y; a[j][2] = t.z; a[j][3] = t.w;
    }
#pragma unroll
    for (int j = 0; j < 4; ++j) {
      float4 t = *(const float4*)&Wsm[k + j][c0];
      wv[j][0] = t.x; wv[j][1] = t.y; wv[j][2] = t.z; wv[j][3] = t.w;
    }
#pragma unroll
    for (int i = 0; i < 4; ++i)
#pragma unroll
      for (int j = 0; j < 4; ++j)
#pragma unroll
        for (int l = 0; l < 4; ++l)
          acc[i][l] = fmaf(a[i][j], wv[j][l], acc[i][l]);
  }
  __syncthreads();

  // GEMM phase 1: Asm = h(self), Wsm = W rows 0..63
  for (int i = tid; i < 4096; i += 256) Wsm[i >> 6][i & 63] = W[i];
#pragma unroll
  for (int i = 0; i < 16; ++i) {
    int nl = i * 4 + w;
    int ng = min(nb + nl, Nn - 1);
    Asm[nl][c] = h[ng * HC + c];
  }
  __syncthreads();
#pragma unroll 4
  for (int k = 0; k < 64; k += 4) {
    float a[4][4], wv[4][4];
#pragma unroll
    for (int j = 0; j < 4; ++j) {
      float4 t = *(const float4*)&Asm[n0 + j][k];
      a[j][0] = t.x; a[j][1] = t.y; a[j][2] = t.z; a[j][3] = t.w;
    }
#pragma unroll
    for (int j = 0; j < 4; ++j) {
      float4 t = *(const float4*)&Wsm[k + j][c0];
      wv[j][0] = t.x; wv[j][1] = t.y; wv[j][2] = t.z; wv[j][3] = t.w;
    }
#pragma unroll
    for (int i = 0; i < 4; ++i)
#pragma unroll
      for (int j = 0; j < 4; ++j)
#pragma unroll
        for (int l = 0; l < 4; ++l)
          acc[i][l] = fmaf(a[i][j], wv[j][l], acc[i][l]);
  }

  float scale[4], shift[4], bias[4];
#pragma unroll
  for (int l = 0; l < 4; ++l) {
    int cc = c0 + l;
    bias[l] = b[cc];
    float sc = gam[cc] * rsqrtf(var[cc] + 1e-5f);
    scale[l] = sc;
    shift[l] = bet[cc] - mean[cc] * sc;
  }
  float o[4][4];
#pragma unroll
  for (int i = 0; i < 4; ++i)
#pragma unroll
    for (int l = 0; l < 4; ++l) {
      float v = fmaxf(acc[i][l] + bias[l], 0.f);
      o[i][l] = fmaxf(fmaf(v, scale[l], shift[l]), 0.f);
    }

  if (!last) {
#pragma unroll
    for (int i = 0; i < 4; ++i) {
      int n = nb + n0 + i;
      if (n < Nn)
        *(float4*)&out[n * HC + c0] = make_float4(o[i][0], o[i][1], o[i][2], o[i][3]);
    }
    return;
  }

  // ---- last layer: fused predictor.  h3 tile -> Asm, Wp1 -> Wsm, GEMM, dot Wp2, reduce ----
  __syncthreads();  // Asm/Wsm still being read above by other waves
#pragma unroll
  for (int i = 0; i < 4; ++i)
    *(float4*)&Asm[n0 + i][c0] = make_float4(o[i][0], o[i][1], o[i][2], o[i][3]);
  for (int i = tid; i < 4096; i += 256) Wsm[i >> 6][i & 63] = Wp1[i];
  __syncthreads();
  float acc2[4][4] = {{0.f}};
#pragma unroll 4
  for (int k = 0; k < 64; k += 4) {
    float a[4][4], wv[4][4];
#pragma unroll
    for (int j = 0; j < 4; ++j) {
      float4 t = *(const float4*)&Asm[n0 + j][k];
      a[j][0] = t.x; a[j][1] = t.y; a[j][2] = t.z; a[j][3] = t.w;
    }
#pragma unroll
    for (int j = 0; j < 4; ++j) {
      float4 t = *(const float4*)&Wsm[k + j][c0];
      wv[j][0] = t.x; wv[j][1] = t.y; wv[j][2] = t.z; wv[j][3] = t.w;
    }
#pragma unroll
    for (int i = 0; i < 4; ++i)
#pragma unroll
      for (int j = 0; j < 4; ++j)
#pragma unroll
        for (int l = 0; l < 4; ++l)
          acc2[i][l] = fmaf(a[i][j], wv[j][l], acc2[i][l]);
  }
  float bias2[4], w2[4];
#pragma unroll
  for (int l = 0; l < 4; ++l) {
    bias2[l] = bp1[c0 + l];
    w2[l] = Wp2[c0 + l];
  }
#pragma unroll
  for (int i = 0; i < 4; ++i) {
    float s = 0.f;
#pragma unroll
    for (int l = 0; l < 4; ++l) {
      float t = fmaxf(acc2[i][l] + bias2[l], 0.f);
      s = fmaf(t, w2[l], s);
    }
    red[n0 + i][tid & 15] = s;
  }
  __syncthreads();
  if (tid < 64) {
    float s = bp2[0];
#pragma unroll
    for (int g = 0; g < 16; ++g) s += red[tid][g];
    int n = nb + tid;
    if (n < Nn) pred[n] = s;
  }
}

extern "C" void kernel_launch(void* const* d_in, const int* in_sizes, int n_in,
                              void* d_out, int out_size, void* d_ws, size_t ws_size,
                              hipStream_t stream) {
  const float* x = (const float*)d_in[0];
  const int* eidx = (const int*)d_in[1];
  const float* eattr = (const float*)d_in[2];
  const float* Wenc = (const float*)d_in[3];
  const float* benc = (const float*)d_in[4];
  const float* Wedge = (const float*)d_in[5];
  const float* bedge = (const float*)d_in[6];
  const float* Wupd = (const float*)d_in[7];
  const float* bupd = (const float*)d_in[8];
  const float* bng = (const float*)d_in[9];
  const float* bnb = (const float*)d_in[10];
  const float* bnm = (const float*)d_in[11];
  const float* bnv = (const float*)d_in[12];
  const float* Wp1 = (const float*)d_in[13];
  const float* bp1 = (const float*)d_in[14];
  const float* Wp2 = (const float*)d_in[15];
  const float* bp2 = (const float*)d_in[16];

  const int Nn = in_sizes[0] / FIN;
  const int E = in_sizes[1] / 2;
  const int* src = eidx;
  const int* dst = eidx + E;
  const int NH = Nn * HC;

  size_t off = 0;
  char* base = (char*)d_ws;
  auto carve = [&](size_t bytes) -> void* {
    void* p = base + off;
    off += (bytes + 255) & ~(size_t)255;
    return p;
  };
  int* row_ptr = (int*)carve((size_t)(Nn + 1) * 4);
  int* cursor = (int*)carve((size_t)(Nn + 1) * 4);
  int* counts = (int*)carve((size_t)(Nn + 1) * 4);
  int* bsums = (int*)carve(256 * 4);
  int* boffs = (int*)carve(256 * 4);
  int2* csr_se = (int2*)carve((size_t)E * 8);
  float* hA = (float*)carve((size_t)NH * 4);
  float* hB = (float*)carve((size_t)NH * 4);
  if (off > ws_size) return;

  int nhB = (NH + 255) / 256;
  int histB = (E + 255) / 256;
  int scan1B = (Nn + 2047) / 2048;
  int scan3B = (Nn + 1 + 255) / 256;
  int updB = (Nn + 63) / 64;

  k_zero<<<scan3B, 256, 0, stream>>>(counts, Nn + 1);
  k_encode<<<nhB, 256, 0, stream>>>(x, Wenc, benc, hA, Nn);
  k_hist<<<histB, 256, 0, stream>>>(dst, counts, E);
  k_scan1<<<scan1B, 256, 0, stream>>>(counts, row_ptr, bsums, Nn);
  k_scan2<<<1, 256, 0, stream>>>(bsums, boffs, scan1B);
  k_scan3<<<scan3B, 256, 0, stream>>>(row_ptr, boffs, cursor, Nn, E);
  k_scatter<<<histB, 256, 0, stream>>>(src, dst, eattr, cursor, csr_se, E);

  float* hc = hA;
  float* hn = hB;
  for (int i = 0; i < LAYERS; ++i) {
    int last = (i == LAYERS - 1) ? 1 : 0;
    k_layer<<<updB, 256, 0, stream>>>(hc, row_ptr, csr_se,
                                      Wedge + i * HC, bedge + i * HC,
                                      Wupd + i * 2 * HC * HC, bupd + i * HC,
                                      bng + i * HC, bnb + i * HC, bnm + i * HC, bnv + i * HC,
                                      hn, Nn,
                                      last, Wp1, bp1, Wp2, bp2, (float*)d_out);
    float* t = hc; hc = hn; hn = t;
  }
}